// Round 1
// 963.993 us; speedup vs baseline: 1.0359x; 1.0359x over previous
//
#include <hip/hip_runtime.h>
#include <stdint.h>

#define DEVINL __device__ __forceinline__

typedef __bf16 bf16x8 __attribute__((ext_vector_type(8)));
typedef float f32x4 __attribute__((ext_vector_type(4)));

DEVINL unsigned short f32_to_bf16(float f) {
  union { float f; uint32_t u; } v;
  v.f = f;
  uint32_t r = v.u + 0x7fffu + ((v.u >> 16) & 1u);  // RNE (inputs are finite)
  return (unsigned short)(r >> 16);
}

// async global->LDS, 16B per lane; LDS dest is wave-uniform base + lane*16
DEVINL void load16_to_lds(const void* g, void* l) {
  __builtin_amdgcn_global_load_lds(
      (const __attribute__((address_space(1))) void*)g,
      (__attribute__((address_space(3))) void*)l, 16, 0, 0);
}

// ---- valid-row compaction -------------------------------------------------
// Deterministic exclusive prefix-sum over mask[8192] (one 1024-thread block,
// 8 entries/thread). ridx[c] = original row of compacted row c; *nv = count.
// ridx padded to a multiple of 128 with row 0 (so downstream staging reads
// valid memory; padded rows' results are never scattered).
__global__ __launch_bounds__(1024) void compact_kernel(
    const int* __restrict__ mask, int* __restrict__ ridx, int* __restrict__ nv) {
  __shared__ int tsum[1024];
  __shared__ int wbase[17];
  const int t = threadIdx.x;
  int flags[8];
  int cnt = 0;
#pragma unroll
  for (int i = 0; i < 8; ++i) {
    flags[i] = (mask[t * 8 + i] != 0) ? 1 : 0;
    cnt += flags[i];
  }
  tsum[t] = cnt;
  __syncthreads();
  if ((t & 63) == 0) {  // lane 0 of each wave: exclusive scan of its 64 counts
    int s = 0;
    for (int i = 0; i < 64; ++i) { int v = tsum[t + i]; tsum[t + i] = s; s += v; }
    wbase[t >> 6] = s;  // wave total (temporarily)
  }
  __syncthreads();
  if (t == 0) {
    int s = 0;
    for (int w = 0; w < 16; ++w) { int v = wbase[w]; wbase[w] = s; s += v; }
    wbase[16] = s;
    *nv = s;
  }
  __syncthreads();
  int base = wbase[t >> 6] + tsum[t];
#pragma unroll
  for (int i = 0; i < 8; ++i)
    if (flags[i]) ridx[base++] = t * 8 + i;
  const int Mv = wbase[16];
  const int Mpad = (Mv + 127) & ~127;
  for (int i = Mv + t; i < Mpad; i += 1024) ridx[i] = 0;
}

// zero-fill out[8192][81] fp32 = 165888 float4 (invalid rows stay zero).
__global__ __launch_bounds__(256) void zero_out_kernel(float4* __restrict__ o) {
  o[(size_t)blockIdx.x * 256 + threadIdx.x] = float4{0.f, 0.f, 0.f, 0.f};
}

// Gather valid rows of features and cast fp32->bf16 into compacted Fb.
// Each thread: 8 fp32 (2x float4 in, 1x uint4 out). 1568 threads cover one
// row (12544). Grid covers worst-case 8192 rows; blocks past Mpad exit.
__global__ __launch_bounds__(256) void gather_cast_kernel(
    const float* __restrict__ feat, const int* __restrict__ ridx,
    const int* __restrict__ nv, unsigned short* __restrict__ out) {
  const int Mpad = ((*nv) + 127) & ~127;
  const unsigned idx = blockIdx.x * 256u + threadIdx.x;
  const unsigned crow = idx / 1568u;
  if ((int)crow >= Mpad) return;
  const int off = (int)(idx - crow * 1568u) * 8;
  const float* src = feat + (size_t)ridx[crow] * 12544 + off;
  float4 a = *reinterpret_cast<const float4*>(src);
  float4 b = *reinterpret_cast<const float4*>(src + 4);
  uint4 p;
  p.x = (uint32_t)f32_to_bf16(a.x) | ((uint32_t)f32_to_bf16(a.y) << 16);
  p.y = (uint32_t)f32_to_bf16(a.z) | ((uint32_t)f32_to_bf16(a.w) << 16);
  p.z = (uint32_t)f32_to_bf16(b.x) | ((uint32_t)f32_to_bf16(b.y) << 16);
  p.w = (uint32_t)f32_to_bf16(b.z) | ((uint32_t)f32_to_bf16(b.w) << 16);
  *reinterpret_cast<uint4*>(out + (size_t)crow * 12544 + off) = p;
}

// W [K][Nsrc] fp32 (row-major) -> Wt [Npad][K] bf16, zero-filled for n >= Nsrc.
// Grid: (K/32, Npad/32), block 256.
__global__ void transpose_cast_kernel(const float* __restrict__ W,
                                      unsigned short* __restrict__ Wt,
                                      int K, int Nsrc) {
  __shared__ float tile[32][33];
  const int k0 = blockIdx.x * 32;
  const int n0 = blockIdx.y * 32;
  const int t = threadIdx.x;
#pragma unroll
  for (int i = 0; i < 4; ++i) {
    int idx = t + 256 * i;
    int r = idx >> 5, c = idx & 31;
    int gn = n0 + c;
    float v = (gn < Nsrc) ? W[(size_t)(k0 + r) * Nsrc + gn] : 0.0f;
    tile[r][c] = v;
  }
  __syncthreads();
#pragma unroll
  for (int i = 0; i < 4; ++i) {
    int idx = t + 256 * i;
    int n = idx >> 5, k = idx & 31;
    Wt[(size_t)(n0 + n) * K + (k0 + k)] = f32_to_bf16(tile[k][n]);
  }
}

// C[m][n] = sum_k A[m][k] * Bt[n][k]  (+bias, then ReLU->bf16 or scatter fp32)
// A rows are COMPACTED (valid rows only, padded to 128 with dup of row 0).
// Blocks with m0 >= Mpad early-exit (device-side count, graph-capture safe).
// Block: 256 threads = 4 waves in 2x2 grid; wave tile = (WM*16) x (WN*16).
// Primary config BM=BN=128: WM=WN=4 -> 16 MFMA : 8 ds_read_b128 per wave-iter.
template <int BM, int BN, bool A_F32, bool RELU_BF16_OUT>
__global__ __launch_bounds__(256) void gemm_kernel(
    const void* __restrict__ Ap, const unsigned short* __restrict__ Bt,
    const float* __restrict__ bias, unsigned short* __restrict__ Hout,
    float* __restrict__ Fout, const int* __restrict__ ridx,
    const int* __restrict__ nv, int K, int Nout, int ldo) {
  constexpr int WM = BM / 32;
  constexpr int WN = BN / 32;
  const int Mv = *nv;
  const int Mpad = (Mv + 127) & ~127;
  const int m0 = blockIdx.y * BM;
  if (m0 >= Mpad) return;

  __shared__ alignas(16) unsigned short Asmem[BM * 32];
  __shared__ alignas(16) unsigned short Bsmem[BN * 32];

  const int tid = threadIdx.x;
  const int wave = tid >> 6, lane = tid & 63;
  const int wm = wave >> 1, wn = wave & 1;
  const int n0 = blockIdx.x * BN;

  const float* Af = (const float*)Ap;
  const unsigned short* Ab = (const unsigned short*)Ap;

  f32x4 acc[WM][WN] = {};

  for (int k0 = 0; k0 < K; k0 += 32) {
    if constexpr (A_F32) {
      // fallback: gather fp32 rows via ridx, convert-on-stage
      constexpr int NF4 = (BM * 32) / (256 * 4);
#pragma unroll
      for (int i = 0; i < NF4; ++i) {
        int idx = tid + 256 * i;
        int r = idx >> 3, c4 = idx & 7;
        float4 v = *reinterpret_cast<const float4*>(
            Af + (size_t)ridx[m0 + r] * K + (k0 + c4 * 4));
        uint2 p;
        p.x = (uint32_t)f32_to_bf16(v.x) | ((uint32_t)f32_to_bf16(v.y) << 16);
        p.y = (uint32_t)f32_to_bf16(v.z) | ((uint32_t)f32_to_bf16(v.w) << 16);
        *reinterpret_cast<uint2*>(&Asmem[r * 32 + c4 * 4]) = p;
      }
    } else {
      // async 16B/lane direct-to-LDS; chunk c = 16 rows = 1024B contiguous.
#pragma unroll
      for (int c = wave; c < BM / 16; c += 4) {
        int row = c * 16 + (lane >> 2);
        load16_to_lds(Ab + (size_t)(m0 + row) * K + (k0 + (lane & 3) * 8),
                      &Asmem[c * 512]);
      }
    }
#pragma unroll
    for (int c = wave; c < BN / 16; c += 4) {
      int row = c * 16 + (lane >> 2);
      load16_to_lds(Bt + (size_t)(n0 + row) * K + (k0 + (lane & 3) * 8),
                    &Bsmem[c * 512]);
    }
    __syncthreads();

    // Fragments: A[m=lane&15][k=quad*8+j], B[n=lane&15][k=quad*8+j]
    bf16x8 a[WM], b[WN];
#pragma unroll
    for (int i = 0; i < WM; ++i)
      a[i] = *reinterpret_cast<const bf16x8*>(
          &Asmem[(wm * WM * 16 + i * 16 + (lane & 15)) * 32 + (lane >> 4) * 8]);
#pragma unroll
    for (int j = 0; j < WN; ++j)
      b[j] = *reinterpret_cast<const bf16x8*>(
          &Bsmem[(wn * WN * 16 + j * 16 + (lane & 15)) * 32 + (lane >> 4) * 8]);
#pragma unroll
    for (int i = 0; i < WM; ++i)
#pragma unroll
      for (int j = 0; j < WN; ++j)
        acc[i][j] = __builtin_amdgcn_mfma_f32_16x16x32_bf16(a[i], b[j],
                                                            acc[i][j], 0, 0, 0);
    __syncthreads();
  }

  // Epilogue. C/D layout: col(n) = lane&15, row(m) = (lane>>4)*4 + reg.
  const int l15 = lane & 15, quad = lane >> 4;
#pragma unroll
  for (int j = 0; j < WN; ++j) {
    int n = n0 + wn * WN * 16 + j * 16 + l15;
    if (n >= Nout) continue;  // only triggers in GEMM3 (Npad=96 > 81)
    float bn = bias[n];
#pragma unroll
    for (int i = 0; i < WM; ++i) {
      int mb = m0 + wm * WM * 16 + i * 16 + quad * 4;
      f32x4 v = acc[i][j];
#pragma unroll
      for (int r = 0; r < 4; ++r) {
        int m = mb + r;
        if constexpr (RELU_BF16_OUT) {
          Hout[(size_t)m * ldo + n] = f32_to_bf16(fmaxf(v[r] + bn, 0.0f));
        } else {
          if (m < Mv) Fout[(size_t)ridx[m] * ldo + n] = v[r] + bn;
        }
      }
    }
  }
}

// Problem constants: B=16, N=512 -> M=8192 rows; FLAT=12544, HID=1024, NC=81.
extern "C" void kernel_launch(void* const* d_in, const int* in_sizes, int n_in,
                              void* d_out, int out_size, void* d_ws,
                              size_t ws_size, hipStream_t stream) {
  const float* feat = (const float*)d_in[0];  // [8192][12544] fp32
  const int* mask = (const int*)d_in[1];      // [8192] int (0/1)
  const float* W1 = (const float*)d_in[2];    // [12544][1024]
  const float* b1 = (const float*)d_in[3];
  const float* W2 = (const float*)d_in[4];    // [1024][1024]
  const float* b2 = (const float*)d_in[5];
  const float* W3 = (const float*)d_in[6];    // [1024][81]
  const float* b3 = (const float*)d_in[7];
  float* out = (float*)d_out;                 // [8192][81] fp32

  char* ws = (char*)d_ws;
  size_t off = 0;
  int* ridx = (int*)(ws + off); off += 32768;                          // [8192]
  int* nv   = (int*)(ws + off); off += 256;                            // count
  unsigned short* W1t = (unsigned short*)(ws + off); off += 25690112;  // [1024][12544]
  unsigned short* W2t = (unsigned short*)(ws + off); off += 2097152;   // [1024][1024]
  unsigned short* W3t = (unsigned short*)(ws + off); off += 196608;    // [96][1024]
  unsigned short* H1  = (unsigned short*)(ws + off); off += 16777216;  // [8192][1024]
  unsigned short* H2  = (unsigned short*)(ws + off); off += 16777216;  // [8192][1024]
  unsigned short* Fb  = (unsigned short*)(ws + off);                   // [8192][12544]
  size_t need = off + 205520896;

  compact_kernel<<<1, 1024, 0, stream>>>(mask, ridx, nv);
  zero_out_kernel<<<648, 256, 0, stream>>>((float4*)out);
  transpose_cast_kernel<<<dim3(392, 32), 256, 0, stream>>>(W1, W1t, 12544, 1024);
  transpose_cast_kernel<<<dim3(32, 32), 256, 0, stream>>>(W2, W2t, 1024, 1024);
  transpose_cast_kernel<<<dim3(32, 3), 256, 0, stream>>>(W3, W3t, 1024, 81);

  if (ws_size >= need) {
    // Gather valid rows + cast to bf16 (reads ~206 MB instead of 411 MB),
    // then all-async GEMM1 on compacted rows (~Mv ~ 4096 of 8192).
    gather_cast_kernel<<<50176, 256, 0, stream>>>(feat, ridx, nv, Fb);
    gemm_kernel<128, 128, false, true><<<dim3(8, 64), 256, 0, stream>>>(
        Fb, W1t, b1, H1, nullptr, ridx, nv, 12544, 1024, 1024);
  } else {
    // Fallback: fused gather+convert-on-stage (slower but no big buffer).
    gemm_kernel<128, 128, true, true><<<dim3(8, 64), 256, 0, stream>>>(
        feat, W1t, b1, H1, nullptr, ridx, nv, 12544, 1024, 1024);
  }
  // GEMM2: h2 = relu(h1 @ W2 + b2) -> bf16 (compacted rows)
  gemm_kernel<128, 128, false, true><<<dim3(8, 64), 256, 0, stream>>>(
      H1, W2t, b2, H2, nullptr, ridx, nv, 1024, 1024, 1024);
  // GEMM3: out[ridx[m]] = h2 @ W3 + b3 (scatter, valid rows only)
  gemm_kernel<32, 96, false, false><<<dim3(1, 256), 256, 0, stream>>>(
      H2, W3t, b3, nullptr, out, ridx, nv, 1024, 81, 81);
}

// Round 2
// 836.486 us; speedup vs baseline: 1.1938x; 1.1524x over previous
//
#include <hip/hip_runtime.h>
#include <stdint.h>

#define DEVINL __device__ __forceinline__

typedef __bf16 bf16x8 __attribute__((ext_vector_type(8)));
typedef float f32x4 __attribute__((ext_vector_type(4)));

DEVINL unsigned short f32_to_bf16(float f) {
  union { float f; uint32_t u; } v;
  v.f = f;
  uint32_t r = v.u + 0x7fffu + ((v.u >> 16) & 1u);  // RNE (inputs are finite)
  return (unsigned short)(r >> 16);
}

// async global->LDS, 16B per lane; LDS dest is wave-uniform base + lane*16
DEVINL void load16_to_lds(const void* g, void* l) {
  __builtin_amdgcn_global_load_lds(
      (const __attribute__((address_space(1))) void*)g,
      (__attribute__((address_space(3))) void*)l, 16, 0, 0);
}

// ---- valid-row compaction -------------------------------------------------
// Deterministic exclusive prefix-sum over mask[8192] (one 1024-thread block,
// 8 entries/thread). ridx[c] = original row of compacted row c; *nv = count.
// ridx padded to a multiple of 128 with row 0.
__global__ __launch_bounds__(1024) void compact_kernel(
    const int* __restrict__ mask, int* __restrict__ ridx, int* __restrict__ nv) {
  __shared__ int tsum[1024];
  __shared__ int wbase[17];
  const int t = threadIdx.x;
  int flags[8];
  int cnt = 0;
#pragma unroll
  for (int i = 0; i < 8; ++i) {
    flags[i] = (mask[t * 8 + i] != 0) ? 1 : 0;
    cnt += flags[i];
  }
  tsum[t] = cnt;
  __syncthreads();
  if ((t & 63) == 0) {  // lane 0 of each wave: exclusive scan of its 64 counts
    int s = 0;
    for (int i = 0; i < 64; ++i) { int v = tsum[t + i]; tsum[t + i] = s; s += v; }
    wbase[t >> 6] = s;  // wave total (temporarily)
  }
  __syncthreads();
  if (t == 0) {
    int s = 0;
    for (int w = 0; w < 16; ++w) { int v = wbase[w]; wbase[w] = s; s += v; }
    wbase[16] = s;
    *nv = s;
  }
  __syncthreads();
  int base = wbase[t >> 6] + tsum[t];
#pragma unroll
  for (int i = 0; i < 8; ++i)
    if (flags[i]) ridx[base++] = t * 8 + i;
  const int Mv = wbase[16];
  const int Mpad = (Mv + 127) & ~127;
  for (int i = Mv + t; i < Mpad; i += 1024) ridx[i] = 0;
}

// zero-fill out[8192][81] fp32 = 165888 float4 (invalid rows stay zero).
__global__ __launch_bounds__(256) void zero_out_kernel(float4* __restrict__ o) {
  o[(size_t)blockIdx.x * 256 + threadIdx.x] = float4{0.f, 0.f, 0.f, 0.f};
}

// Gather valid rows of features and cast fp32->bf16 into compacted Fb.
__global__ __launch_bounds__(256) void gather_cast_kernel(
    const float* __restrict__ feat, const int* __restrict__ ridx,
    const int* __restrict__ nv, unsigned short* __restrict__ out) {
  const int Mpad = ((*nv) + 127) & ~127;
  const unsigned idx = blockIdx.x * 256u + threadIdx.x;
  const unsigned crow = idx / 1568u;
  if ((int)crow >= Mpad) return;
  const int off = (int)(idx - crow * 1568u) * 8;
  const float* src = feat + (size_t)ridx[crow] * 12544 + off;
  float4 a = *reinterpret_cast<const float4*>(src);
  float4 b = *reinterpret_cast<const float4*>(src + 4);
  uint4 p;
  p.x = (uint32_t)f32_to_bf16(a.x) | ((uint32_t)f32_to_bf16(a.y) << 16);
  p.y = (uint32_t)f32_to_bf16(a.z) | ((uint32_t)f32_to_bf16(a.w) << 16);
  p.z = (uint32_t)f32_to_bf16(b.x) | ((uint32_t)f32_to_bf16(b.y) << 16);
  p.w = (uint32_t)f32_to_bf16(b.z) | ((uint32_t)f32_to_bf16(b.w) << 16);
  *reinterpret_cast<uint4*>(out + (size_t)crow * 12544 + off) = p;
}

// W [K][Nsrc] fp32 (row-major) -> Wt [Npad][K] bf16, zero-filled for n >= Nsrc.
__global__ void transpose_cast_kernel(const float* __restrict__ W,
                                      unsigned short* __restrict__ Wt,
                                      int K, int Nsrc) {
  __shared__ float tile[32][33];
  const int k0 = blockIdx.x * 32;
  const int n0 = blockIdx.y * 32;
  const int t = threadIdx.x;
#pragma unroll
  for (int i = 0; i < 4; ++i) {
    int idx = t + 256 * i;
    int r = idx >> 5, c = idx & 31;
    int gn = n0 + c;
    float v = (gn < Nsrc) ? W[(size_t)(k0 + r) * Nsrc + gn] : 0.0f;
    tile[r][c] = v;
  }
  __syncthreads();
#pragma unroll
  for (int i = 0; i < 4; ++i) {
    int idx = t + 256 * i;
    int n = idx >> 5, k = idx & 31;
    Wt[(size_t)(n0 + n) * K + (k0 + k)] = f32_to_bf16(tile[k][n]);
  }
}

// Sum the 4 split-K partials + bias, ReLU, cast -> bf16 H1.
// Grid: 8192 blocks x 256 threads; block = one compacted row, thread = 4 cols.
__global__ __launch_bounds__(256) void reduce_relu_kernel(
    const float* __restrict__ P, const float* __restrict__ bias,
    const int* __restrict__ nv, unsigned short* __restrict__ H) {
  const int Mpad = ((*nv) + 127) & ~127;
  const int m = blockIdx.x;
  if (m >= Mpad) return;
  const int n = threadIdx.x * 4;
  f32x4 s = {};
#pragma unroll
  for (int c = 0; c < 4; ++c) {
    f32x4 v = *reinterpret_cast<const f32x4*>(
        P + ((size_t)c * 8192 + m) * 1024 + n);
    s[0] += v[0]; s[1] += v[1]; s[2] += v[2]; s[3] += v[3];
  }
  f32x4 bv = *reinterpret_cast<const f32x4*>(bias + n);
  uint2 o;
  o.x = (uint32_t)f32_to_bf16(fmaxf(s[0] + bv[0], 0.0f)) |
        ((uint32_t)f32_to_bf16(fmaxf(s[1] + bv[1], 0.0f)) << 16);
  o.y = (uint32_t)f32_to_bf16(fmaxf(s[2] + bv[2], 0.0f)) |
        ((uint32_t)f32_to_bf16(fmaxf(s[3] + bv[3], 0.0f)) << 16);
  *reinterpret_cast<uint2*>(H + (size_t)m * 1024 + n) = o;
}

// C[m][n] = sum_k A[m][k] * Bt[n][k], 2-phase double-buffered staging.
// A rows are COMPACTED (valid rows only, padded to 128 with dup of row 0).
// Per k-tile: STAGE(next buf) -> compute(cur buf) -> __syncthreads (drains
// vmcnt: next tile staged; barrier: cur buf free to overwrite). Loads for
// tile t+1 overlap the MFMAs of tile t; one barrier per tile instead of two.
// blockIdx.z = split-K chunk (k_len = K / gridDim.z).
// OMODE: 0 = bias+ReLU->bf16 Hout, 1 = bias+scatter fp32 via ridx (m<Mv),
//        2 = raw fp32 partial -> Fout[(z*8192+m)*ldo+n] (no bias).
template <int BM, int BN, bool A_F32, int OMODE>
__global__ __launch_bounds__(256) void gemm_kernel(
    const void* __restrict__ Ap, const unsigned short* __restrict__ Bt,
    const float* __restrict__ bias, unsigned short* __restrict__ Hout,
    float* __restrict__ Fout, const int* __restrict__ ridx,
    const int* __restrict__ nv, int K, int k_len, int Nout, int ldo) {
  constexpr int WM = BM / 32;
  constexpr int WN = BN / 32;
  const int Mv = *nv;
  const int Mpad = (Mv + 127) & ~127;
  const int m0 = blockIdx.y * BM;
  if (m0 >= Mpad) return;

  __shared__ alignas(16) unsigned short As[2][BM * 32];
  __shared__ alignas(16) unsigned short Bs[2][BN * 32];

  const int tid = threadIdx.x;
  const int wave = tid >> 6, lane = tid & 63;
  const int wm = wave >> 1, wn = wave & 1;
  const int n0 = blockIdx.x * BN;
  const int ks = blockIdx.z * k_len;
  const int ke = ks + k_len;

  const float* Af = (const float*)Ap;
  const unsigned short* Ab = (const unsigned short*)Ap;

  f32x4 acc[WM][WN] = {};

  auto stage = [&](int b, int k0) {
    if constexpr (A_F32) {
      // fallback: gather fp32 rows via ridx, convert-on-stage
      constexpr int NF4 = (BM * 32) / (256 * 4);
#pragma unroll
      for (int i = 0; i < NF4; ++i) {
        int idx = tid + 256 * i;
        int r = idx >> 3, c4 = idx & 7;
        float4 v = *reinterpret_cast<const float4*>(
            Af + (size_t)ridx[m0 + r] * K + (k0 + c4 * 4));
        uint2 p;
        p.x = (uint32_t)f32_to_bf16(v.x) | ((uint32_t)f32_to_bf16(v.y) << 16);
        p.y = (uint32_t)f32_to_bf16(v.z) | ((uint32_t)f32_to_bf16(v.w) << 16);
        *reinterpret_cast<uint2*>(&As[b][r * 32 + c4 * 4]) = p;
      }
    } else {
      // async 16B/lane direct-to-LDS; chunk c = 16 rows = 1024B contiguous.
#pragma unroll
      for (int c = wave; c < BM / 16; c += 4) {
        int row = c * 16 + (lane >> 2);
        load16_to_lds(Ab + (size_t)(m0 + row) * K + (k0 + (lane & 3) * 8),
                      &As[b][c * 512]);
      }
    }
#pragma unroll
    for (int c = wave; c < BN / 16; c += 4) {
      int row = c * 16 + (lane >> 2);
      load16_to_lds(Bt + (size_t)(n0 + row) * K + (k0 + (lane & 3) * 8),
                    &Bs[b][c * 512]);
    }
  };

  auto compute = [&](int b) {
    // Fragments: A[m=lane&15][k=quad*8+j], B[n=lane&15][k=quad*8+j]
    bf16x8 a[WM], bb[WN];
#pragma unroll
    for (int i = 0; i < WM; ++i)
      a[i] = *reinterpret_cast<const bf16x8*>(
          &As[b][(wm * WM * 16 + i * 16 + (lane & 15)) * 32 + (lane >> 4) * 8]);
#pragma unroll
    for (int j = 0; j < WN; ++j)
      bb[j] = *reinterpret_cast<const bf16x8*>(
          &Bs[b][(wn * WN * 16 + j * 16 + (lane & 15)) * 32 + (lane >> 4) * 8]);
#pragma unroll
    for (int i = 0; i < WM; ++i)
#pragma unroll
      for (int j = 0; j < WN; ++j)
        acc[i][j] = __builtin_amdgcn_mfma_f32_16x16x32_bf16(a[i], bb[j],
                                                            acc[i][j], 0, 0, 0);
  };

  stage(0, ks);
  __syncthreads();
  int cur = 0;
  for (int k0 = ks + 32; k0 < ke; k0 += 32) {
    stage(cur ^ 1, k0);  // issue next tile's loads BEFORE computing current
    compute(cur);
    __syncthreads();     // drains vmcnt(0): next staged; cur now overwritable
    cur ^= 1;
  }
  compute(cur);

  // Epilogue. C/D layout: col(n) = lane&15, row(m) = (lane>>4)*4 + reg.
  const int l15 = lane & 15, quad = lane >> 4;
#pragma unroll
  for (int j = 0; j < WN; ++j) {
    int n = n0 + wn * WN * 16 + j * 16 + l15;
    if (n >= Nout) continue;  // only triggers in GEMM3 (Npad=96 > 81)
    float bn = (OMODE == 2) ? 0.0f : bias[n];
#pragma unroll
    for (int i = 0; i < WM; ++i) {
      int mb = m0 + wm * WM * 16 + i * 16 + quad * 4;
      f32x4 v = acc[i][j];
#pragma unroll
      for (int r = 0; r < 4; ++r) {
        int m = mb + r;
        if constexpr (OMODE == 0) {
          Hout[(size_t)m * ldo + n] = f32_to_bf16(fmaxf(v[r] + bn, 0.0f));
        } else if constexpr (OMODE == 1) {
          if (m < Mv) Fout[(size_t)ridx[m] * ldo + n] = v[r] + bn;
        } else {
          Fout[((size_t)blockIdx.z * 8192 + m) * (size_t)ldo + n] = v[r];
        }
      }
    }
  }
}

// Problem constants: B=16, N=512 -> M=8192 rows; FLAT=12544, HID=1024, NC=81.
extern "C" void kernel_launch(void* const* d_in, const int* in_sizes, int n_in,
                              void* d_out, int out_size, void* d_ws,
                              size_t ws_size, hipStream_t stream) {
  const float* feat = (const float*)d_in[0];  // [8192][12544] fp32
  const int* mask = (const int*)d_in[1];      // [8192] int (0/1)
  const float* W1 = (const float*)d_in[2];    // [12544][1024]
  const float* b1 = (const float*)d_in[3];
  const float* W2 = (const float*)d_in[4];    // [1024][1024]
  const float* b2 = (const float*)d_in[5];
  const float* W3 = (const float*)d_in[6];    // [1024][81]
  const float* b3 = (const float*)d_in[7];
  float* out = (float*)d_out;                 // [8192][81] fp32

  char* ws = (char*)d_ws;
  size_t off = 0;
  int* ridx = (int*)(ws + off); off += 32768;                          // [8192]
  int* nv   = (int*)(ws + off); off += 256;                            // count
  unsigned short* W1t = (unsigned short*)(ws + off); off += 25690112;  // [1024][12544]
  unsigned short* W2t = (unsigned short*)(ws + off); off += 2097152;   // [1024][1024]
  unsigned short* W3t = (unsigned short*)(ws + off); off += 196608;    // [96][1024]
  unsigned short* H1  = (unsigned short*)(ws + off); off += 16777216;  // [8192][1024]
  unsigned short* H2  = (unsigned short*)(ws + off); off += 16777216;  // [8192][1024]
  unsigned short* Fb  = (unsigned short*)(ws + off); off += 205520896; // [8192][12544]
  size_t need_base = off;
  float* P = (float*)(ws + off); off += 134217728;  // [4][8192][1024] fp32
  size_t need_split = off;

  compact_kernel<<<1, 1024, 0, stream>>>(mask, ridx, nv);
  zero_out_kernel<<<648, 256, 0, stream>>>((float4*)out);
  transpose_cast_kernel<<<dim3(392, 32), 256, 0, stream>>>(W1, W1t, 12544, 1024);
  transpose_cast_kernel<<<dim3(32, 32), 256, 0, stream>>>(W2, W2t, 1024, 1024);
  transpose_cast_kernel<<<dim3(32, 3), 256, 0, stream>>>(W3, W3t, 1024, 81);

  if (ws_size >= need_split) {
    // Gather+cast valid rows to bf16, split-K=4 GEMM1 (4 blocks/CU working),
    // deterministic reduce (+bias+ReLU+bf16).
    gather_cast_kernel<<<50176, 256, 0, stream>>>(feat, ridx, nv, Fb);
    gemm_kernel<128, 128, false, 2><<<dim3(8, 64, 4), 256, 0, stream>>>(
        Fb, W1t, b1, nullptr, P, ridx, nv, 12544, 3136, 1024, 1024);
    reduce_relu_kernel<<<8192, 256, 0, stream>>>(P, b1, nv, H1);
  } else if (ws_size >= need_base) {
    // No room for partials: single-pass 2-phase GEMM1 on compacted bf16 rows.
    gather_cast_kernel<<<50176, 256, 0, stream>>>(feat, ridx, nv, Fb);
    gemm_kernel<128, 128, false, 0><<<dim3(8, 64, 1), 256, 0, stream>>>(
        Fb, W1t, b1, H1, nullptr, ridx, nv, 12544, 12544, 1024, 1024);
  } else {
    // Fallback: fused gather+convert-on-stage from fp32 features.
    gemm_kernel<128, 128, true, 0><<<dim3(8, 64, 1), 256, 0, stream>>>(
        feat, W1t, b1, H1, nullptr, ridx, nv, 12544, 12544, 1024, 1024);
  }
  // GEMM2: h2 = relu(h1 @ W2 + b2) -> bf16 (compacted rows)
  gemm_kernel<128, 128, false, 0><<<dim3(8, 64, 1), 256, 0, stream>>>(
      H1, W2t, b2, H2, nullptr, ridx, nv, 1024, 1024, 1024, 1024);
  // GEMM3: out[ridx[m]] = h2 @ W3 + b3 (scatter, valid rows only)
  gemm_kernel<32, 96, false, 1><<<dim3(1, 256, 1), 256, 0, stream>>>(
      H2, W3t, b3, nullptr, out, ridx, nv, 1024, 1024, 81, 81);
}

// Round 3
// 816.729 us; speedup vs baseline: 1.2227x; 1.0242x over previous
//
#include <hip/hip_runtime.h>
#include <stdint.h>

#define DEVINL __device__ __forceinline__

typedef __bf16 bf16x8 __attribute__((ext_vector_type(8)));
typedef float f32x4 __attribute__((ext_vector_type(4)));

DEVINL unsigned short f32_to_bf16(float f) {
  union { float f; uint32_t u; } v;
  v.f = f;
  uint32_t r = v.u + 0x7fffu + ((v.u >> 16) & 1u);  // RNE (inputs are finite)
  return (unsigned short)(r >> 16);
}

// async global->LDS, 16B per lane; LDS dest is wave-uniform base + lane*16
DEVINL void load16_to_lds(const void* g, void* l) {
  __builtin_amdgcn_global_load_lds(
      (const __attribute__((address_space(1))) void*)g,
      (__attribute__((address_space(3))) void*)l, 16, 0, 0);
}

// ---- valid-row compaction -------------------------------------------------
// Deterministic exclusive prefix-sum over mask[8192] (one 1024-thread block,
// 8 entries/thread). ridx[c] = original row of compacted row c; *nv = count.
// ridx padded to a multiple of 128 with row 0.
__global__ __launch_bounds__(1024) void compact_kernel(
    const int* __restrict__ mask, int* __restrict__ ridx, int* __restrict__ nv) {
  __shared__ int tsum[1024];
  __shared__ int wbase[17];
  const int t = threadIdx.x;
  int flags[8];
  int cnt = 0;
#pragma unroll
  for (int i = 0; i < 8; ++i) {
    flags[i] = (mask[t * 8 + i] != 0) ? 1 : 0;
    cnt += flags[i];
  }
  tsum[t] = cnt;
  __syncthreads();
  if ((t & 63) == 0) {  // lane 0 of each wave: exclusive scan of its 64 counts
    int s = 0;
    for (int i = 0; i < 64; ++i) { int v = tsum[t + i]; tsum[t + i] = s; s += v; }
    wbase[t >> 6] = s;  // wave total (temporarily)
  }
  __syncthreads();
  if (t == 0) {
    int s = 0;
    for (int w = 0; w < 16; ++w) { int v = wbase[w]; wbase[w] = s; s += v; }
    wbase[16] = s;
    *nv = s;
  }
  __syncthreads();
  int base = wbase[t >> 6] + tsum[t];
#pragma unroll
  for (int i = 0; i < 8; ++i)
    if (flags[i]) ridx[base++] = t * 8 + i;
  const int Mv = wbase[16];
  const int Mpad = (Mv + 127) & ~127;
  for (int i = Mv + t; i < Mpad; i += 1024) ridx[i] = 0;
}

// zero-fill out[8192][81] fp32 = 165888 float4 (invalid rows stay zero).
__global__ __launch_bounds__(256) void zero_out_kernel(float4* __restrict__ o) {
  o[(size_t)blockIdx.x * 256 + threadIdx.x] = float4{0.f, 0.f, 0.f, 0.f};
}

// W [K][Nsrc] fp32 (row-major) -> Wt [Npad][K] bf16, zero-filled for n >= Nsrc.
__global__ void transpose_cast_kernel(const float* __restrict__ W,
                                      unsigned short* __restrict__ Wt,
                                      int K, int Nsrc) {
  __shared__ float tile[32][33];
  const int k0 = blockIdx.x * 32;
  const int n0 = blockIdx.y * 32;
  const int t = threadIdx.x;
#pragma unroll
  for (int i = 0; i < 4; ++i) {
    int idx = t + 256 * i;
    int r = idx >> 5, c = idx & 31;
    int gn = n0 + c;
    float v = (gn < Nsrc) ? W[(size_t)(k0 + r) * Nsrc + gn] : 0.0f;
    tile[r][c] = v;
  }
  __syncthreads();
#pragma unroll
  for (int i = 0; i < 4; ++i) {
    int idx = t + 256 * i;
    int n = idx >> 5, k = idx & 31;
    Wt[(size_t)(n0 + n) * K + (k0 + k)] = f32_to_bf16(tile[k][n]);
  }
}

// Sum the 4 split-K partials + bias, ReLU, cast -> bf16 H1.
// Grid: 8192 blocks x 256 threads; block = one compacted row, thread = 4 cols.
__global__ __launch_bounds__(256) void reduce_relu_kernel(
    const float* __restrict__ P, const float* __restrict__ bias,
    const int* __restrict__ nv, unsigned short* __restrict__ H) {
  const int Mpad = ((*nv) + 127) & ~127;
  const int m = blockIdx.x;
  if (m >= Mpad) return;
  const int n = threadIdx.x * 4;
  f32x4 s = {};
#pragma unroll
  for (int c = 0; c < 4; ++c) {
    f32x4 v = *reinterpret_cast<const f32x4*>(
        P + ((size_t)c * 8192 + m) * 1024 + n);
    s[0] += v[0]; s[1] += v[1]; s[2] += v[2]; s[3] += v[3];
  }
  f32x4 bv = *reinterpret_cast<const f32x4*>(bias + n);
  uint2 o;
  o.x = (uint32_t)f32_to_bf16(fmaxf(s[0] + bv[0], 0.0f)) |
        ((uint32_t)f32_to_bf16(fmaxf(s[1] + bv[1], 0.0f)) << 16);
  o.y = (uint32_t)f32_to_bf16(fmaxf(s[2] + bv[2], 0.0f)) |
        ((uint32_t)f32_to_bf16(fmaxf(s[3] + bv[3], 0.0f)) << 16);
  *reinterpret_cast<uint2*>(H + (size_t)m * 1024 + n) = o;
}

// C[m][n] = sum_k A[m][k] * Bt[n][k], 2-phase double-buffered staging.
// A rows are COMPACTED (valid rows only, padded to 128 with dup of row 0).
// Per k-tile: load A(next)->regs / async-stage B(next) -> MFMA(cur) ->
// convert+ds_write A(next) -> barrier. HBM latency of next tile hides under
// the MFMAs of the current tile (T14 split for the fp32 A path).
// blockIdx.z = split-K chunk (k_len = K / gridDim.z).
// OMODE: 0 = bias+ReLU->bf16 Hout, 1 = bias+scatter fp32 via ridx (m<Mv),
//        2 = raw fp32 partial -> Fout[(z*8192+m)*ldo+n] (no bias).
// SWZ: XCD-chunked remap, REQUIRES launch grid exactly (8,64,4). y-fastest
// decode so each XCD gets all-y sweeps of 4 (x,z) pairs: W1t panels
// (4 x 802 KB) stay L2-resident, dead blocks (y >= Mpad/BM) spread evenly.
template <int BM, int BN, bool A_F32, int OMODE, bool SWZ>
__global__ __launch_bounds__(256, 4) void gemm_kernel(
    const void* __restrict__ Ap, const unsigned short* __restrict__ Bt,
    const float* __restrict__ bias, unsigned short* __restrict__ Hout,
    float* __restrict__ Fout, const int* __restrict__ ridx,
    const int* __restrict__ nv, int K, int k_len, int Nout, int ldo) {
  constexpr int WM = BM / 32;
  constexpr int WN = BN / 32;
  int bx, by, bz;
  if constexpr (SWZ) {
    int orig = blockIdx.x + ((blockIdx.y + (blockIdx.z << 6)) << 3);  // (8,64,4)
    int swz = ((orig & 7) << 8) | (orig >> 3);  // bijective: nwg=2048, q=256
    by = swz & 63; bx = (swz >> 6) & 7; bz = swz >> 9;
  } else {
    bx = blockIdx.x; by = blockIdx.y; bz = blockIdx.z;
  }
  const int Mv = *nv;
  const int Mpad = (Mv + 127) & ~127;
  const int m0 = by * BM;
  if (m0 >= Mpad) return;

  __shared__ alignas(16) unsigned short As[2][BM * 32];
  __shared__ alignas(16) unsigned short Bs[2][BN * 32];

  const int tid = threadIdx.x;
  const int wave = tid >> 6, lane = tid & 63;
  const int wm = wave >> 1, wn = wave & 1;
  const int n0 = bx * BN;
  const int ks = bz * k_len;
  const int ke = ks + k_len;

  const float* Af = (const float*)Ap;
  const unsigned short* Ab = (const unsigned short*)Ap;

  f32x4 acc[WM][WN] = {};

  // fp32-A path: per-thread gathered row pointers (8 threads x 32 cols/row).
  const float* aptr[4];
  if constexpr (A_F32) {
    static_assert(BM == 128, "fp32 A staging assumes BM=128");
#pragma unroll
    for (int i = 0; i < 4; ++i) {
      int r = (tid >> 3) + 32 * i;
      aptr[i] = Af + (size_t)ridx[m0 + r] * K + (tid & 7) * 4;
    }
  }

  auto loadA_f32 = [&](int k0, float4* va) {
#pragma unroll
    for (int i = 0; i < 4; ++i)
      va[i] = *reinterpret_cast<const float4*>(aptr[i] + k0);
  };
  auto writeA_f32 = [&](int b, const float4* va) {
#pragma unroll
    for (int i = 0; i < 4; ++i) {
      int r = (tid >> 3) + 32 * i, c4 = tid & 7;
      uint2 p;
      p.x = (uint32_t)f32_to_bf16(va[i].x) | ((uint32_t)f32_to_bf16(va[i].y) << 16);
      p.y = (uint32_t)f32_to_bf16(va[i].z) | ((uint32_t)f32_to_bf16(va[i].w) << 16);
      *reinterpret_cast<uint2*>(&As[b][r * 32 + c4 * 4]) = p;
    }
  };
  auto stageA_async = [&](int b, int k0) {
#pragma unroll
    for (int c = wave; c < BM / 16; c += 4) {
      int row = c * 16 + (lane >> 2);
      load16_to_lds(Ab + (size_t)(m0 + row) * K + (k0 + (lane & 3) * 8),
                    &As[b][c * 512]);
    }
  };
  auto stageB = [&](int b, int k0) {
#pragma unroll
    for (int c = wave; c < BN / 16; c += 4) {
      int row = c * 16 + (lane >> 2);
      load16_to_lds(Bt + (size_t)(n0 + row) * K + (k0 + (lane & 3) * 8),
                    &Bs[b][c * 512]);
    }
  };

  auto compute = [&](int b) {
    // Fragments: A[m=lane&15][k=quad*8+j], B[n=lane&15][k=quad*8+j]
    bf16x8 a[WM], bb[WN];
#pragma unroll
    for (int i = 0; i < WM; ++i)
      a[i] = *reinterpret_cast<const bf16x8*>(
          &As[b][(wm * WM * 16 + i * 16 + (lane & 15)) * 32 + (lane >> 4) * 8]);
#pragma unroll
    for (int j = 0; j < WN; ++j)
      bb[j] = *reinterpret_cast<const bf16x8*>(
          &Bs[b][(wn * WN * 16 + j * 16 + (lane & 15)) * 32 + (lane >> 4) * 8]);
#pragma unroll
    for (int i = 0; i < WM; ++i)
#pragma unroll
      for (int j = 0; j < WN; ++j)
        acc[i][j] = __builtin_amdgcn_mfma_f32_16x16x32_bf16(a[i], bb[j],
                                                            acc[i][j], 0, 0, 0);
  };

  float4 va[4];
  if constexpr (A_F32) loadA_f32(ks, va); else stageA_async(0, ks);
  stageB(0, ks);
  if constexpr (A_F32) writeA_f32(0, va);
  __syncthreads();
  int cur = 0;
  for (int k0 = ks + 32; k0 < ke; k0 += 32) {
    if constexpr (A_F32) loadA_f32(k0, va); else stageA_async(cur ^ 1, k0);
    stageB(cur ^ 1, k0);   // async loads for next tile in flight...
    compute(cur);          // ...under the MFMAs of the current tile
    if constexpr (A_F32) writeA_f32(cur ^ 1, va);  // waitcnt lands after MFMAs
    __syncthreads();       // drains vmcnt+lgkmcnt: next staged, cur reusable
    cur ^= 1;
  }
  compute(cur);

  // Epilogue. C/D layout: col(n) = lane&15, row(m) = (lane>>4)*4 + reg.
  const int l15 = lane & 15, quad = lane >> 4;
#pragma unroll
  for (int j = 0; j < WN; ++j) {
    int n = n0 + wn * WN * 16 + j * 16 + l15;
    if (n >= Nout) continue;  // only triggers in GEMM3 (Npad=96 > 81)
    float bn = (OMODE == 2) ? 0.0f : bias[n];
#pragma unroll
    for (int i = 0; i < WM; ++i) {
      int mb = m0 + wm * WM * 16 + i * 16 + quad * 4;
      f32x4 v = acc[i][j];
#pragma unroll
      for (int r = 0; r < 4; ++r) {
        int m = mb + r;
        if constexpr (OMODE == 0) {
          Hout[(size_t)m * ldo + n] = f32_to_bf16(fmaxf(v[r] + bn, 0.0f));
        } else if constexpr (OMODE == 1) {
          if (m < Mv) Fout[(size_t)ridx[m] * ldo + n] = v[r] + bn;
        } else {
          Fout[((size_t)bz * 8192 + m) * (size_t)ldo + n] = v[r];
        }
      }
    }
  }
}

// Problem constants: B=16, N=512 -> M=8192 rows; FLAT=12544, HID=1024, NC=81.
extern "C" void kernel_launch(void* const* d_in, const int* in_sizes, int n_in,
                              void* d_out, int out_size, void* d_ws,
                              size_t ws_size, hipStream_t stream) {
  const float* feat = (const float*)d_in[0];  // [8192][12544] fp32
  const int* mask = (const int*)d_in[1];      // [8192] int (0/1)
  const float* W1 = (const float*)d_in[2];    // [12544][1024]
  const float* b1 = (const float*)d_in[3];
  const float* W2 = (const float*)d_in[4];    // [1024][1024]
  const float* b2 = (const float*)d_in[5];
  const float* W3 = (const float*)d_in[6];    // [1024][81]
  const float* b3 = (const float*)d_in[7];
  float* out = (float*)d_out;                 // [8192][81] fp32

  char* ws = (char*)d_ws;
  size_t off = 0;
  int* ridx = (int*)(ws + off); off += 32768;                          // [8192]
  int* nv   = (int*)(ws + off); off += 256;                            // count
  unsigned short* W1t = (unsigned short*)(ws + off); off += 25690112;  // [1024][12544]
  unsigned short* W2t = (unsigned short*)(ws + off); off += 2097152;   // [1024][1024]
  unsigned short* W3t = (unsigned short*)(ws + off); off += 196608;    // [96][1024]
  unsigned short* H1  = (unsigned short*)(ws + off); off += 16777216;  // [8192][1024]
  unsigned short* H2  = (unsigned short*)(ws + off); off += 16777216;  // [8192][1024]
  size_t need_base = off;
  float* P = (float*)(ws + off); off += 134217728;  // [4][8192][1024] fp32
  size_t need_split = off;

  compact_kernel<<<1, 1024, 0, stream>>>(mask, ridx, nv);
  zero_out_kernel<<<648, 256, 0, stream>>>((float4*)out);
  transpose_cast_kernel<<<dim3(392, 32), 256, 0, stream>>>(W1, W1t, 12544, 1024);
  transpose_cast_kernel<<<dim3(32, 32), 256, 0, stream>>>(W2, W2t, 1024, 1024);
  transpose_cast_kernel<<<dim3(32, 3), 256, 0, stream>>>(W3, W3t, 1024, 81);

  if (ws_size >= need_split) {
    // GEMM1 fused gather+cast (fp32 A staged in-kernel), split-K=4,
    // XCD-swizzled; then deterministic reduce (+bias+ReLU+bf16).
    gemm_kernel<128, 128, true, 2, true><<<dim3(8, 64, 4), 256, 0, stream>>>(
        feat, W1t, b1, nullptr, P, ridx, nv, 12544, 3136, 1024, 1024);
    reduce_relu_kernel<<<8192, 256, 0, stream>>>(P, b1, nv, H1);
  } else {
    // No room for partials: single-pass fused GEMM1 (latency-bound but safe).
    gemm_kernel<128, 128, true, 0, false><<<dim3(8, 64, 1), 256, 0, stream>>>(
        feat, W1t, b1, H1, nullptr, ridx, nv, 12544, 12544, 1024, 1024);
  }
  // GEMM2: h2 = relu(h1 @ W2 + b2) -> bf16; BM=64 -> 2 working blocks/CU.
  gemm_kernel<64, 128, false, 0, false><<<dim3(8, 128, 1), 256, 0, stream>>>(
      H1, W2t, b2, H2, nullptr, ridx, nv, 1024, 1024, 1024, 1024);
  // GEMM3: out[ridx[m]] = h2 @ W3 + b3 (scatter, valid rows only)
  gemm_kernel<32, 96, false, 1, false><<<dim3(1, 256, 1), 256, 0, stream>>>(
      H2, W3t, b3, nullptr, out, ridx, nv, 1024, 1024, 81, 81);
}